// Round 14
// baseline (1639.199 us; speedup 1.0000x reference)
//
#include <hip/hip_runtime.h>

#define THREADS 256
#define BSH 7        // rows per bucket = 128
#define EPB 8192     // edges per binning block (256 threads x 32)

typedef _Float16 f16;
typedef _Float16 f16x8 __attribute__((ext_vector_type(8)));
typedef _Float16 f16x4 __attribute__((ext_vector_type(4)));
typedef float f32x4 __attribute__((ext_vector_type(4)));

// ---------------- front: hist + ALL weight converts + zero stats (1 dispatch) ----------------
// blocks [0, nblk): per-(bucket, block) histogram
// blocks [nblk, nblk+512): Wt1 = (f16)W1^T   (K=512, N=256)
// blocks [+512, +768):     Wt2 = (f16)W2^T   (K=256, N=256)
// blocks [+768, +832):     Wt3 = (f16)W3^T   (K=256, N=64)

__global__ __launch_bounds__(256) void k_front(
    const int* __restrict__ rows, int* __restrict__ cnt2d, int e, int nblk, int nb,
    const float* __restrict__ W1, f16* __restrict__ Wt1,
    const float* __restrict__ W2, f16* __restrict__ Wt2,
    const float* __restrict__ W3, f16* __restrict__ Wt3,
    float* __restrict__ statZero, unsigned long long* __restrict__ tpub, int ntiles) {
  int t = threadIdx.x;
  if (blockIdx.x < nblk) {
    __shared__ int hist[1024];
    int blk = blockIdx.x;
    for (int i = t; i < nb; i += 256) hist[i] = 0;
    __syncthreads();
    int eb = blk * EPB;
#pragma unroll 4
    for (int it = 0; it < 32; ++it) {
      int i = eb + it * 256 + t;
      if (i < e) atomicAdd(&hist[rows[i] >> BSH], 1);
    }
    __syncthreads();
    for (int i = t; i < nb; i += 256) cnt2d[i * nblk + blk] = hist[i];
  } else {
    int cb = blockIdx.x - nblk;
    if (cb == 0) {
#pragma unroll
      for (int j = 0; j < 4; ++j) statZero[j * 256 + t] = 0.f;
      for (int i = t; i < ntiles; i += 256) tpub[i] = 0ULL;
    }
    if (cb < 512) {
      int i = cb * 256 + t;  // over N*K = 256*512
      int n = i >> 9, k = i & 511;
      Wt1[i] = (f16)W1[(size_t)k * 256 + n];
    } else if (cb < 768) {
      int i = (cb - 512) * 256 + t;  // 256*256
      int n = i >> 8, k = i & 255;
      Wt2[i] = (f16)W2[(size_t)k * 256 + n];
    } else {
      int i = (cb - 768) * 256 + t;  // 64*256
      int n = i >> 8, k = i & 255;
      Wt3[i] = (f16)W3[(size_t)k * 64 + n];
    }
  }
}

// ---------------- single-pass decoupled-lookback exclusive scan ----------------

__global__ __launch_bounds__(256) void k_scanDL(
    const int* __restrict__ cnt, int* __restrict__ outp,
    unsigned long long* __restrict__ tpub, int n) {
  __shared__ int sh[256];
  __shared__ int sPrefix;
  int tile = blockIdx.x, t = threadIdx.x;
  int base = tile * 1024 + t * 4;
  int v[4];
#pragma unroll
  for (int j = 0; j < 4; ++j) {
    int idx = base + j;
    v[j] = (idx < n) ? cnt[idx] : 0;
  }
  int tot = v[0] + v[1] + v[2] + v[3];
  sh[t] = tot;
  __syncthreads();
  for (int off = 1; off < 256; off <<= 1) {
    int x = 0;
    if (t >= off) x = sh[t - off];
    __syncthreads();
    sh[t] += x;
    __syncthreads();
  }
  int blockTot = sh[255];
  int run = sh[t] - tot;

  if (t == 0) {
    if (tile == 0) {
      sPrefix = 0;
      atomicExch(&tpub[0], ((unsigned long long)(unsigned)blockTot << 2) | 2ULL);
    } else {
      atomicExch(&tpub[tile], ((unsigned long long)(unsigned)blockTot << 2) | 1ULL);
      long long sum = 0;
      int pred = tile - 1;
      while (true) {
        unsigned long long s = atomicAdd(&tpub[pred], 0ULL);
        unsigned st = (unsigned)(s & 3ULL);
        if (st == 2) { sum += (long long)(s >> 2); break; }
        if (st == 1) { sum += (long long)(s >> 2); --pred; }
      }
      sPrefix = (int)sum;
      atomicExch(&tpub[tile],
                 ((unsigned long long)(unsigned)(sum + blockTot) << 2) | 2ULL);
    }
  }
  __syncthreads();
  int pfx = sPrefix;
#pragma unroll
  for (int j = 0; j < 4; ++j) {
    int idx = base + j;
    if (idx < n) outp[idx] = run + pfx;
    run += v[j];
  }
  if (tile == gridDim.x - 1 && t == 0) outp[n] = pfx + blockTot;
}

// ---------------- GEMM device body ----------------
// Csup[M][BN] = A'[M][K] @ Wt^T, f16 out. BM=128, 4 waves.
// BNF: A' = A*sc[k]+sf[k], sc/sf derived in-kernel from sums (BN stats).

template <int BN, bool AF16, bool BNF>
__device__ __forceinline__ void gemm_dev(
    int mblk, const void* __restrict__ Ap, const f16* __restrict__ Wt,
    f16* __restrict__ Csup, int M, int K,
    const float* __restrict__ sums, int nrows, char* smem) {
  constexpr int BM = 128;
  constexpr int BK = 32;
  constexpr int LDT = BK + 8;
  f16 (*As)[LDT] = (f16(*)[LDT])smem;
  f16 (*Bs)[LDT] = (f16(*)[LDT])(smem + BM * LDT * 2);
  __shared__ float scL[256], sfL[256];

  const int tid = threadIdx.x;
  const int wave = tid >> 6;
  const int lane = tid & 63;
  const int m0 = mblk * BM;
  constexpr int WM = (BN == 256) ? 8 : 2;
  constexpr int WN = 4;
  const int wrow = (BN == 256) ? 0 : wave * 32;
  const int wcol = (BN == 256) ? wave * 64 : 0;
  const int l15 = lane & 15;
  const int lq = lane >> 4;

  const int arow = tid >> 1;
  const int akofs = (tid & 1) * 16;
  const int srow = tid >> 2;
  const int skofs = (tid & 3) * 8;
  constexpr int BROWS = BN / 64;

  if constexpr (BNF) {
    // K == 256 for all BNF uses
    float inv = 1.0f / (float)nrows;
    float mean = sums[tid] * inv;
    float var = sums[256 + tid] * inv - mean * mean;
    float rstd = rsqrtf(var + 1e-5f);
    scL[tid] = rstd;
    sfL[tid] = -mean * rstd;
    __syncthreads();
  }

  f32x4 acc[WM][WN] = {};

  for (int k0 = 0; k0 < K; k0 += BK) {
    f16x8 a16[2];
    int gr = m0 + arow;
    if constexpr (AF16) {
      if (gr < M) {
        const f16* ap = (const f16*)Ap + (size_t)gr * K + k0 + akofs;
        a16[0] = *(const f16x8*)ap;
        a16[1] = *(const f16x8*)(ap + 8);
        if constexpr (BNF) {
#pragma unroll
          for (int h = 0; h < 2; ++h)
#pragma unroll
            for (int j = 0; j < 8; ++j) {
              int k = k0 + akofs + h * 8 + j;
              a16[h][j] = (f16)((float)a16[h][j] * scL[k] + sfL[k]);
            }
        }
      } else {
#pragma unroll
        for (int j = 0; j < 8; ++j) { a16[0][j] = (f16)0.f; a16[1][j] = (f16)0.f; }
      }
    } else {
      float va[16];
      if (gr < M) {
        const float* ap = (const float*)Ap + (size_t)gr * K + k0 + akofs;
#pragma unroll
        for (int q = 0; q < 4; ++q) *(float4*)&va[q * 4] = *(const float4*)(ap + q * 4);
      } else {
#pragma unroll
        for (int j = 0; j < 16; ++j) va[j] = 0.f;
      }
#pragma unroll
      for (int j = 0; j < 8; ++j) { a16[0][j] = (f16)va[j]; a16[1][j] = (f16)va[8 + j]; }
    }

    f16x8 vb[BROWS];
#pragma unroll
    for (int j = 0; j < BROWS; ++j)
      vb[j] = *(const f16x8*)(Wt + (size_t)(srow + j * 64) * K + k0 + skofs);

    __syncthreads();
    *(f16x8*)&As[arow][akofs] = a16[0];
    *(f16x8*)&As[arow][akofs + 8] = a16[1];
#pragma unroll
    for (int j = 0; j < BROWS; ++j) *(f16x8*)&Bs[srow + j * 64][skofs] = vb[j];
    __syncthreads();

    f16x8 af[WM], bf[WN];
#pragma unroll
    for (int m = 0; m < WM; ++m)
      af[m] = *(const f16x8*)&As[wrow + m * 16 + l15][lq * 8];
#pragma unroll
    for (int n = 0; n < WN; ++n)
      bf[n] = *(const f16x8*)&Bs[wcol + n * 16 + l15][lq * 8];
#pragma unroll
    for (int m = 0; m < WM; ++m)
#pragma unroll
      for (int n = 0; n < WN; ++n)
        acc[m][n] = __builtin_amdgcn_mfma_f32_16x16x32_f16(af[m], bf[n], acc[m][n], 0, 0, 0);
  }

#pragma unroll
  for (int m = 0; m < WM; ++m) {
#pragma unroll
    for (int r = 0; r < 4; ++r) {
      int row = m0 + wrow + m * 16 + lq * 4 + r;
      if (row < M) {
        f16* cp = Csup + (size_t)row * BN + wcol + l15;
#pragma unroll
        for (int n = 0; n < WN; ++n) cp[n * 16] = (f16)acc[m][n][r];
      }
    }
  }
}

template <int BN, bool AF16, bool BNF>
__global__ __launch_bounds__(256) void k_gemm_mfma(
    const void* __restrict__ Ap, const f16* __restrict__ Wt,
    f16* __restrict__ Csup, int M, int K,
    const float* __restrict__ sums, int nrows) {
  __shared__ __align__(16) char smem[(128 + BN) * 40 * 2];
  gemm_dev<BN, AF16, BNF>(blockIdx.x, Ap, Wt, Csup, M, K, sums, nrows, smem);
}

// ---------------- merged: k_bin (blocks < nblk) + layer-1 GEMM (rest) ----------------

__global__ __launch_bounds__(256) void k_bin_gemm(
    const int* __restrict__ rows, const int* __restrict__ cols,
    const float* __restrict__ w, const int* __restrict__ off2d,
    int2* __restrict__ temp, int e, int nblk, int nb,
    const float* __restrict__ x, const f16* __restrict__ Wt1,
    f16* __restrict__ sup, int M) {
  __shared__ __align__(16) char smem[(128 + 256) * 40 * 2];
  int t = threadIdx.x;
  if (blockIdx.x < nblk) {
    int* base = (int*)smem;
    int* cursor = (int*)smem + 1024;
    int blk = blockIdx.x;
    for (int i = t; i < nb; i += 256) {
      base[i] = off2d[i * nblk + blk];
      cursor[i] = 0;
    }
    __syncthreads();
    int eb = blk * EPB;
#pragma unroll 4
    for (int it = 0; it < 32; ++it) {
      int i = eb + it * 256 + t;
      if (i < e) {
        int r = rows[i];
        int b = r >> BSH;
        int pos = base[b] + atomicAdd(&cursor[b], 1);
        temp[pos] = make_int2(((r & 127) << 17) | cols[i], __float_as_int(w[i]));
      }
    }
  } else {
    gemm_dev<256, false, false>(blockIdx.x - nblk, x, Wt1, sup, M, 512, nullptr, 0, smem);
  }
}

// ---------------- scatter: one block per 128-row bucket ----------------

__global__ __launch_bounds__(256) void k_scatter(
    const int2* __restrict__ temp, const int* __restrict__ off2d,
    int* __restrict__ rowptr, int2* __restrict__ ed,
    int n, int e, int nblk, int nb) {
  __shared__ int rowCnt[128];
  __shared__ int rowBase[128];
  __shared__ int rowCur[128];
  int b = blockIdx.x, t = threadIdx.x;
  int r0 = b << BSH;
  int nr = min(128, n - r0);
  int start = off2d[b * nblk];
  int end = off2d[(b + 1) * nblk];
  if (t < 128) rowCnt[t] = 0;
  __syncthreads();
  for (int p = start + t; p < end; p += 256)
    atomicAdd(&rowCnt[temp[p].x >> 17], 1);
  __syncthreads();
  int v = 0;
  if (t < 128) {
    v = rowCnt[t];
    rowBase[t] = v;
  }
  __syncthreads();
  for (int off = 1; off < 128; off <<= 1) {
    int x = 0;
    if (t < 128 && t >= off) x = rowBase[t - off];
    __syncthreads();
    if (t < 128) rowBase[t] += x;
    __syncthreads();
  }
  if (t < 128) {
    int excl = rowBase[t] - v;
    rowBase[t] = excl;
    rowCur[t] = 0;
    if (t < nr) rowptr[r0 + t] = start + excl;
  }
  if (b == nb - 1 && t == 0) rowptr[n] = e;
  __syncthreads();
  for (int p = start + t; p < end; p += 256) {
    int2 ei = temp[p];
    int ro = ei.x >> 17;
    int slot = start + rowBase[ro] + atomicAdd(&rowCur[ro], 1);
    ed[slot] = make_int2(ei.x & 0x1FFFF, ei.y);
  }
}

// ---------------- Aggregation D=256 + fused BN column stats ----------------
// one WAVE per row, 16-deep gather pipeline; block epilogue reduces 4 rows'
// values + squares via LDS and atomicAdds into sums[512].

__global__ __launch_bounds__(256) void k_agg256(
    const f16* __restrict__ sup, const int* __restrict__ rowptr,
    const int2* __restrict__ ed, const float* __restrict__ bias,
    f16* __restrict__ out, float* __restrict__ sums, int n) {
  __shared__ float shs[4][256];
  int tid = threadIdx.x;
  int wave = tid >> 6;
  int wid = (blockIdx.x * THREADS + tid) >> 6;
  int lane = tid & 63;
  bool valid = wid < n;
  int p0 = 0, p1 = 0;
  if (valid) { p0 = rowptr[wid]; p1 = rowptr[wid + 1]; }

  const f16x4* supv = (const f16x4*)sup;
  float acc[4][4] = {};
  int p = p0;
  for (; p + 16 <= p1; p += 16) {
    int2 e[16];
#pragma unroll
    for (int j = 0; j < 16; ++j) e[j] = ed[p + j];
    f16x4 v[16];
#pragma unroll
    for (int j = 0; j < 16; ++j) v[j] = supv[(size_t)e[j].x * 64 + lane];
#pragma unroll
    for (int j = 0; j < 16; ++j) {
      float wt = __int_as_float(e[j].y);
      acc[j & 3][0] += wt * (float)v[j][0];
      acc[j & 3][1] += wt * (float)v[j][1];
      acc[j & 3][2] += wt * (float)v[j][2];
      acc[j & 3][3] += wt * (float)v[j][3];
    }
  }
  for (; p + 4 <= p1; p += 4) {
    int2 e[4];
#pragma unroll
    for (int j = 0; j < 4; ++j) e[j] = ed[p + j];
    f16x4 v[4];
#pragma unroll
    for (int j = 0; j < 4; ++j) v[j] = supv[(size_t)e[j].x * 64 + lane];
#pragma unroll
    for (int j = 0; j < 4; ++j) {
      float wt = __int_as_float(e[j].y);
      acc[j][0] += wt * (float)v[j][0];
      acc[j][1] += wt * (float)v[j][1];
      acc[j][2] += wt * (float)v[j][2];
      acc[j][3] += wt * (float)v[j][3];
    }
  }
  for (; p < p1; ++p) {
    int2 e0 = ed[p];
    float wt = __int_as_float(e0.y);
    f16x4 v = supv[(size_t)e0.x * 64 + lane];
    acc[0][0] += wt * (float)v[0];
    acc[0][1] += wt * (float)v[1];
    acc[0][2] += wt * (float)v[2];
    acc[0][3] += wt * (float)v[3];
  }
  float4 b = *(const float4*)(bias + lane * 4);
  float r0 = 0.f, r1 = 0.f, r2 = 0.f, r3 = 0.f;
  if (valid) {
    r0 = fmaxf(acc[0][0] + acc[1][0] + acc[2][0] + acc[3][0] + b.x, 0.f);
    r1 = fmaxf(acc[0][1] + acc[1][1] + acc[2][1] + acc[3][1] + b.y, 0.f);
    r2 = fmaxf(acc[0][2] + acc[1][2] + acc[2][2] + acc[3][2] + b.z, 0.f);
    r3 = fmaxf(acc[0][3] + acc[1][3] + acc[2][3] + acc[3][3] + b.w, 0.f);
    f16x4 r;
    r[0] = (f16)r0; r[1] = (f16)r1; r[2] = (f16)r2; r[3] = (f16)r3;
    *(f16x4*)(out + (size_t)wid * 256 + lane * 4) = r;
  }
  // --- fused column stats ---
  *(float4*)&shs[wave][lane * 4] = make_float4(r0, r1, r2, r3);
  __syncthreads();
  float s = shs[0][tid] + shs[1][tid] + shs[2][tid] + shs[3][tid];
  __syncthreads();
  *(float4*)&shs[wave][lane * 4] =
      make_float4(r0 * r0, r1 * r1, r2 * r2, r3 * r3);
  __syncthreads();
  float s2 = shs[0][tid] + shs[1][tid] + shs[2][tid] + shs[3][tid];
  atomicAdd(&sums[tid], s);
  atomicAdd(&sums[256 + tid], s2);
}

// ---------------- Aggregation D=64: one WAVE per row, quarter-wave edge slots ----

__global__ __launch_bounds__(256) void k_agg64(
    const f16* __restrict__ sup, const int* __restrict__ rowptr,
    const int2* __restrict__ ed, const float* __restrict__ bias,
    float* __restrict__ out, int n) {
  int wid = (blockIdx.x * THREADS + threadIdx.x) >> 6;
  int lane = threadIdx.x & 63;
  if (wid >= n) return;
  int p0 = rowptr[wid], p1 = rowptr[wid + 1];
  int q = lane >> 4;
  int hl = lane & 15;

  const f16x4* supv = (const f16x4*)sup;
  float acc[2][4] = {};
  int p = p0;
  for (; p + 32 <= p1; p += 32) {
    int2 e[8];
#pragma unroll
    for (int j = 0; j < 8; ++j) e[j] = ed[p + 4 * j + q];
    f16x4 v[8];
#pragma unroll
    for (int j = 0; j < 8; ++j) v[j] = supv[(size_t)e[j].x * 16 + hl];
#pragma unroll
    for (int j = 0; j < 8; ++j) {
      float wt = __int_as_float(e[j].y);
      acc[j & 1][0] += wt * (float)v[j][0];
      acc[j & 1][1] += wt * (float)v[j][1];
      acc[j & 1][2] += wt * (float)v[j][2];
      acc[j & 1][3] += wt * (float)v[j][3];
    }
  }
  for (; p + 4 <= p1; p += 4) {
    int2 e0 = ed[p + q];
    float wt = __int_as_float(e0.y);
    f16x4 v = supv[(size_t)e0.x * 16 + hl];
    acc[0][0] += wt * (float)v[0];
    acc[0][1] += wt * (float)v[1];
    acc[0][2] += wt * (float)v[2];
    acc[0][3] += wt * (float)v[3];
  }
  if (p < p1) {
    int idx = p + q;
    int c = 0;
    float wt = 0.f;
    if (idx < p1) {
      int2 e0 = ed[idx];
      c = e0.x;
      wt = __int_as_float(e0.y);
    }
    f16x4 v = supv[(size_t)c * 16 + hl];
    acc[0][0] += wt * (float)v[0];
    acc[0][1] += wt * (float)v[1];
    acc[0][2] += wt * (float)v[2];
    acc[0][3] += wt * (float)v[3];
  }
  float t0 = acc[0][0] + acc[1][0];
  float t1 = acc[0][1] + acc[1][1];
  float t2 = acc[0][2] + acc[1][2];
  float t3 = acc[0][3] + acc[1][3];
  t0 += __shfl_xor(t0, 16); t0 += __shfl_xor(t0, 32);
  t1 += __shfl_xor(t1, 16); t1 += __shfl_xor(t1, 32);
  t2 += __shfl_xor(t2, 16); t2 += __shfl_xor(t2, 32);
  t3 += __shfl_xor(t3, 16); t3 += __shfl_xor(t3, 32);
  if (q == 0) {
    float4 b = *(const float4*)(bias + hl * 4);
    float4 res;
    res.x = fmaxf(t0 + b.x, 0.f);
    res.y = fmaxf(t1 + b.y, 0.f);
    res.z = fmaxf(t2 + b.z, 0.f);
    res.w = fmaxf(t3 + b.w, 0.f);
    *(float4*)(out + (size_t)wid * 64 + hl * 4) = res;
  }
}

// ---------------- launch ----------------

extern "C" void kernel_launch(void* const* d_in, const int* in_sizes, int n_in,
                              void* d_out, int out_size, void* d_ws, size_t ws_size,
                              hipStream_t stream) {
  const float* x = (const float*)d_in[0];
  const int* ei = (const int*)d_in[1];
  const float* ew = (const float*)d_in[2];
  const float* W1 = (const float*)d_in[3];
  const float* b1 = (const float*)d_in[4];
  const float* W2 = (const float*)d_in[5];
  const float* b2 = (const float*)d_in[6];
  const float* W3 = (const float*)d_in[7];
  const float* b3 = (const float*)d_in[8];
  float* out = (float*)d_out;

  const int N = in_sizes[0] / 512;  // 100000
  const int E = in_sizes[2];        // 3200000

  const int NB = (N + 127) >> BSH;            // 128-row buckets (782)
  const int NBLK = (E + EPB - 1) / EPB;       // binning blocks (391)
  const int scanN = NB * NBLK;
  const int ntiles = (scanN + 1023) / 1024;

  char* p = (char*)d_ws;
  auto alloc = [&](size_t bytes) {
    void* r = (void*)p;
    p += (bytes + 255) & ~(size_t)255;
    return r;
  };
  int* rowptr = (int*)alloc((size_t)(N + 1) * 4);
  int* cnt2d = (int*)alloc((size_t)scanN * 4);
  int* off2d = (int*)alloc((size_t)(scanN + 1) * 4);
  unsigned long long* tpub = (unsigned long long*)alloc((size_t)ntiles * 8);
  float* statZ = (float*)alloc(1024 * 4);
  float* sumsA = statZ;
  float* sumsB = statZ + 512;
  f16* Wt1 = (f16*)alloc((size_t)512 * 256 * 2);
  f16* Wt2 = (f16*)alloc((size_t)256 * 256 * 2);
  f16* Wt3 = (f16*)alloc((size_t)256 * 64 * 2);
  int2* temp = (int2*)alloc((size_t)E * 8);
  int2* ed = (int2*)alloc((size_t)E * 8);
  f16* sup = (f16*)alloc((size_t)N * 256 * 2);
  f16* act = (f16*)alloc((size_t)N * 256 * 2);

  const int* rows = ei;
  const int* colsIn = ei + E;

  const int gemmBlocks = (N + 127) / 128;
  const int aggBlocks = (N * 64 + THREADS - 1) / THREADS;

  // --- front: hist + Wt1/Wt2/Wt3 converts + zero stats (1 dispatch) ---
  k_front<<<NBLK + 832, 256, 0, stream>>>(
      rows, cnt2d, E, NBLK, NB, W1, Wt1, W2, Wt2, W3, Wt3, statZ, tpub, ntiles);

  // --- single-pass scan ---
  k_scanDL<<<ntiles, 256, 0, stream>>>(cnt2d, off2d, tpub, scanN);

  // --- bin + layer-1 GEMM (1 dispatch, independent halves) ---
  k_bin_gemm<<<NBLK + gemmBlocks, 256, 0, stream>>>(
      rows, colsIn, ew, off2d, temp, E, NBLK, NB, x, Wt1, sup, N);

  // --- scatter into final CSR ---
  k_scatter<<<NB, 256, 0, stream>>>(temp, off2d, rowptr, ed, N, E, NBLK, NB);

  // --- Layer 1 agg (+BN1 stats) ---
  k_agg256<<<aggBlocks, 256, 0, stream>>>(sup, rowptr, ed, b1, act, sumsA, N);

  // --- Layer 2: GEMM folds BN1 into A-path; agg (+BN2 stats) ---
  k_gemm_mfma<256, true, true><<<gemmBlocks, 256, 0, stream>>>(
      act, Wt2, sup, N, 256, sumsA, N);
  k_agg256<<<aggBlocks, 256, 0, stream>>>(sup, rowptr, ed, b2, act, sumsB, N);

  // --- Layer 3: GEMM folds BN2; agg64 ---
  k_gemm_mfma<64, true, true><<<gemmBlocks, 256, 0, stream>>>(
      act, Wt3, sup, N, 256, sumsB, N);
  k_agg64<<<aggBlocks, 256, 0, stream>>>(sup, rowptr, ed, b3, out, N);
}

// Round 15
// 863.087 us; speedup vs baseline: 1.8992x; 1.8992x over previous
//
#include <hip/hip_runtime.h>

#define THREADS 256
#define BSH 7        // rows per bucket = 128
#define EPB 8192     // edges per binning block (256 threads x 32)

typedef _Float16 f16;
typedef _Float16 f16x8 __attribute__((ext_vector_type(8)));
typedef _Float16 f16x4 __attribute__((ext_vector_type(4)));
typedef float f32x4 __attribute__((ext_vector_type(4)));

// ---------------- front: hist + ALL weight converts + zero stats (1 dispatch) ----------------

__global__ __launch_bounds__(256) void k_front(
    const int* __restrict__ rows, int* __restrict__ cnt2d, int e, int nblk, int nb,
    const float* __restrict__ W1, f16* __restrict__ Wt1,
    const float* __restrict__ W2, f16* __restrict__ Wt2,
    const float* __restrict__ W3, f16* __restrict__ Wt3,
    float* __restrict__ statZero, unsigned long long* __restrict__ tpub, int ntiles) {
  int t = threadIdx.x;
  if (blockIdx.x < nblk) {
    __shared__ int hist[1024];
    int blk = blockIdx.x;
    for (int i = t; i < nb; i += 256) hist[i] = 0;
    __syncthreads();
    int eb = blk * EPB;
#pragma unroll 4
    for (int it = 0; it < 32; ++it) {
      int i = eb + it * 256 + t;
      if (i < e) atomicAdd(&hist[rows[i] >> BSH], 1);
    }
    __syncthreads();
    for (int i = t; i < nb; i += 256) cnt2d[i * nblk + blk] = hist[i];
  } else {
    int cb = blockIdx.x - nblk;
    if (cb == 0) {
#pragma unroll
      for (int j = 0; j < 4; ++j) statZero[j * 256 + t] = 0.f;
      for (int i = t; i < ntiles; i += 256) tpub[i] = 0ULL;
    }
    if (cb < 512) {
      int i = cb * 256 + t;  // over N*K = 256*512
      int n = i >> 9, k = i & 511;
      Wt1[i] = (f16)W1[(size_t)k * 256 + n];
    } else if (cb < 768) {
      int i = (cb - 512) * 256 + t;  // 256*256
      int n = i >> 8, k = i & 255;
      Wt2[i] = (f16)W2[(size_t)k * 256 + n];
    } else {
      int i = (cb - 768) * 256 + t;  // 64*256
      int n = i >> 8, k = i & 255;
      Wt3[i] = (f16)W3[(size_t)k * 64 + n];
    }
  }
}

// ---------------- single-pass decoupled-lookback exclusive scan ----------------

__global__ __launch_bounds__(256) void k_scanDL(
    const int* __restrict__ cnt, int* __restrict__ outp,
    unsigned long long* __restrict__ tpub, int n) {
  __shared__ int sh[256];
  __shared__ int sPrefix;
  int tile = blockIdx.x, t = threadIdx.x;
  int base = tile * 1024 + t * 4;
  int v[4];
#pragma unroll
  for (int j = 0; j < 4; ++j) {
    int idx = base + j;
    v[j] = (idx < n) ? cnt[idx] : 0;
  }
  int tot = v[0] + v[1] + v[2] + v[3];
  sh[t] = tot;
  __syncthreads();
  for (int off = 1; off < 256; off <<= 1) {
    int x = 0;
    if (t >= off) x = sh[t - off];
    __syncthreads();
    sh[t] += x;
    __syncthreads();
  }
  int blockTot = sh[255];
  int run = sh[t] - tot;

  if (t == 0) {
    if (tile == 0) {
      sPrefix = 0;
      atomicExch(&tpub[0], ((unsigned long long)(unsigned)blockTot << 2) | 2ULL);
    } else {
      atomicExch(&tpub[tile], ((unsigned long long)(unsigned)blockTot << 2) | 1ULL);
      long long sum = 0;
      int pred = tile - 1;
      while (true) {
        unsigned long long s = atomicAdd(&tpub[pred], 0ULL);
        unsigned st = (unsigned)(s & 3ULL);
        if (st == 2) { sum += (long long)(s >> 2); break; }
        if (st == 1) { sum += (long long)(s >> 2); --pred; }
      }
      sPrefix = (int)sum;
      atomicExch(&tpub[tile],
                 ((unsigned long long)(unsigned)(sum + blockTot) << 2) | 2ULL);
    }
  }
  __syncthreads();
  int pfx = sPrefix;
#pragma unroll
  for (int j = 0; j < 4; ++j) {
    int idx = base + j;
    if (idx < n) outp[idx] = run + pfx;
    run += v[j];
  }
  if (tile == gridDim.x - 1 && t == 0) outp[n] = pfx + blockTot;
}

// ---------------- GEMM device body ----------------
// Csup[M][BN] = A'[M][K] @ Wt^T, f16 out. BM=128, 4 waves.
// BNF: A' = A*sc[k]+sf[k], sc/sf derived in-kernel from sums (BN stats).

template <int BN, bool AF16, bool BNF>
__device__ __forceinline__ void gemm_dev(
    int mblk, const void* __restrict__ Ap, const f16* __restrict__ Wt,
    f16* __restrict__ Csup, int M, int K,
    const float* __restrict__ sums, int nrows, char* smem) {
  constexpr int BM = 128;
  constexpr int BK = 32;
  constexpr int LDT = BK + 8;
  f16 (*As)[LDT] = (f16(*)[LDT])smem;
  f16 (*Bs)[LDT] = (f16(*)[LDT])(smem + BM * LDT * 2);
  __shared__ float scL[256], sfL[256];

  const int tid = threadIdx.x;
  const int wave = tid >> 6;
  const int lane = tid & 63;
  const int m0 = mblk * BM;
  constexpr int WM = (BN == 256) ? 8 : 2;
  constexpr int WN = 4;
  const int wrow = (BN == 256) ? 0 : wave * 32;
  const int wcol = (BN == 256) ? wave * 64 : 0;
  const int l15 = lane & 15;
  const int lq = lane >> 4;

  const int arow = tid >> 1;
  const int akofs = (tid & 1) * 16;
  const int srow = tid >> 2;
  const int skofs = (tid & 3) * 8;
  constexpr int BROWS = BN / 64;

  if constexpr (BNF) {
    float inv = 1.0f / (float)nrows;
    float mean = sums[tid] * inv;
    float var = sums[256 + tid] * inv - mean * mean;
    float rstd = rsqrtf(var + 1e-5f);
    scL[tid] = rstd;
    sfL[tid] = -mean * rstd;
    __syncthreads();
  }

  f32x4 acc[WM][WN] = {};

  for (int k0 = 0; k0 < K; k0 += BK) {
    f16x8 a16[2];
    int gr = m0 + arow;
    if constexpr (AF16) {
      if (gr < M) {
        const f16* ap = (const f16*)Ap + (size_t)gr * K + k0 + akofs;
        a16[0] = *(const f16x8*)ap;
        a16[1] = *(const f16x8*)(ap + 8);
        if constexpr (BNF) {
#pragma unroll
          for (int h = 0; h < 2; ++h)
#pragma unroll
            for (int j = 0; j < 8; ++j) {
              int k = k0 + akofs + h * 8 + j;
              a16[h][j] = (f16)((float)a16[h][j] * scL[k] + sfL[k]);
            }
        }
      } else {
#pragma unroll
        for (int j = 0; j < 8; ++j) { a16[0][j] = (f16)0.f; a16[1][j] = (f16)0.f; }
      }
    } else {
      float va[16];
      if (gr < M) {
        const float* ap = (const float*)Ap + (size_t)gr * K + k0 + akofs;
#pragma unroll
        for (int q = 0; q < 4; ++q) *(float4*)&va[q * 4] = *(const float4*)(ap + q * 4);
      } else {
#pragma unroll
        for (int j = 0; j < 16; ++j) va[j] = 0.f;
      }
#pragma unroll
      for (int j = 0; j < 8; ++j) { a16[0][j] = (f16)va[j]; a16[1][j] = (f16)va[8 + j]; }
    }

    f16x8 vb[BROWS];
#pragma unroll
    for (int j = 0; j < BROWS; ++j)
      vb[j] = *(const f16x8*)(Wt + (size_t)(srow + j * 64) * K + k0 + skofs);

    __syncthreads();
    *(f16x8*)&As[arow][akofs] = a16[0];
    *(f16x8*)&As[arow][akofs + 8] = a16[1];
#pragma unroll
    for (int j = 0; j < BROWS; ++j) *(f16x8*)&Bs[srow + j * 64][skofs] = vb[j];
    __syncthreads();

    f16x8 af[WM], bf[WN];
#pragma unroll
    for (int m = 0; m < WM; ++m)
      af[m] = *(const f16x8*)&As[wrow + m * 16 + l15][lq * 8];
#pragma unroll
    for (int n = 0; n < WN; ++n)
      bf[n] = *(const f16x8*)&Bs[wcol + n * 16 + l15][lq * 8];
#pragma unroll
    for (int m = 0; m < WM; ++m)
#pragma unroll
      for (int n = 0; n < WN; ++n)
        acc[m][n] = __builtin_amdgcn_mfma_f32_16x16x32_f16(af[m], bf[n], acc[m][n], 0, 0, 0);
  }

#pragma unroll
  for (int m = 0; m < WM; ++m) {
#pragma unroll
    for (int r = 0; r < 4; ++r) {
      int row = m0 + wrow + m * 16 + lq * 4 + r;
      if (row < M) {
        f16* cp = Csup + (size_t)row * BN + wcol + l15;
#pragma unroll
        for (int n = 0; n < WN; ++n) cp[n * 16] = (f16)acc[m][n][r];
      }
    }
  }
}

template <int BN, bool AF16, bool BNF>
__global__ __launch_bounds__(256) void k_gemm_mfma(
    const void* __restrict__ Ap, const f16* __restrict__ Wt,
    f16* __restrict__ Csup, int M, int K,
    const float* __restrict__ sums, int nrows) {
  __shared__ __align__(16) char smem[(128 + BN) * 40 * 2];
  gemm_dev<BN, AF16, BNF>(blockIdx.x, Ap, Wt, Csup, M, K, sums, nrows, smem);
}

// ---------------- merged: k_bin (blocks < nblk) + layer-1 GEMM (rest) ----------------

__global__ __launch_bounds__(256) void k_bin_gemm(
    const int* __restrict__ rows, const int* __restrict__ cols,
    const float* __restrict__ w, const int* __restrict__ off2d,
    int2* __restrict__ temp, int e, int nblk, int nb,
    const float* __restrict__ x, const f16* __restrict__ Wt1,
    f16* __restrict__ sup, int M) {
  __shared__ __align__(16) char smem[(128 + 256) * 40 * 2];
  int t = threadIdx.x;
  if (blockIdx.x < nblk) {
    int* base = (int*)smem;
    int* cursor = (int*)smem + 1024;
    int blk = blockIdx.x;
    for (int i = t; i < nb; i += 256) {
      base[i] = off2d[i * nblk + blk];
      cursor[i] = 0;
    }
    __syncthreads();
    int eb = blk * EPB;
#pragma unroll 4
    for (int it = 0; it < 32; ++it) {
      int i = eb + it * 256 + t;
      if (i < e) {
        int r = rows[i];
        int b = r >> BSH;
        int pos = base[b] + atomicAdd(&cursor[b], 1);
        temp[pos] = make_int2(((r & 127) << 17) | cols[i], __float_as_int(w[i]));
      }
    }
  } else {
    gemm_dev<256, false, false>(blockIdx.x - nblk, x, Wt1, sup, M, 512, nullptr, 0, smem);
  }
}

// ---------------- scatter: one block per 128-row bucket ----------------

__global__ __launch_bounds__(256) void k_scatter(
    const int2* __restrict__ temp, const int* __restrict__ off2d,
    int* __restrict__ rowptr, int2* __restrict__ ed,
    int n, int e, int nblk, int nb) {
  __shared__ int rowCnt[128];
  __shared__ int rowBase[128];
  __shared__ int rowCur[128];
  int b = blockIdx.x, t = threadIdx.x;
  int r0 = b << BSH;
  int nr = min(128, n - r0);
  int start = off2d[b * nblk];
  int end = off2d[(b + 1) * nblk];
  if (t < 128) rowCnt[t] = 0;
  __syncthreads();
  for (int p = start + t; p < end; p += 256)
    atomicAdd(&rowCnt[temp[p].x >> 17], 1);
  __syncthreads();
  int v = 0;
  if (t < 128) {
    v = rowCnt[t];
    rowBase[t] = v;
  }
  __syncthreads();
  for (int off = 1; off < 128; off <<= 1) {
    int x = 0;
    if (t < 128 && t >= off) x = rowBase[t - off];
    __syncthreads();
    if (t < 128) rowBase[t] += x;
    __syncthreads();
  }
  if (t < 128) {
    int excl = rowBase[t] - v;
    rowBase[t] = excl;
    rowCur[t] = 0;
    if (t < nr) rowptr[r0 + t] = start + excl;
  }
  if (b == nb - 1 && t == 0) rowptr[n] = e;
  __syncthreads();
  for (int p = start + t; p < end; p += 256) {
    int2 ei = temp[p];
    int ro = ei.x >> 17;
    int slot = start + rowBase[ro] + atomicAdd(&rowCur[ro], 1);
    ed[slot] = make_int2(ei.x & 0x1FFFF, ei.y);
  }
}

// ---------------- Aggregation D=256: one WAVE per row, 16-deep gather pipeline ----

__global__ __launch_bounds__(256) void k_agg256(
    const f16* __restrict__ sup, const int* __restrict__ rowptr,
    const int2* __restrict__ ed, const float* __restrict__ bias,
    f16* __restrict__ out, int n) {
  int wid = (blockIdx.x * THREADS + threadIdx.x) >> 6;
  int lane = threadIdx.x & 63;
  if (wid >= n) return;
  int p0 = rowptr[wid], p1 = rowptr[wid + 1];

  const f16x4* supv = (const f16x4*)sup;
  float acc[4][4] = {};
  int p = p0;
  for (; p + 16 <= p1; p += 16) {
    int2 e[16];
#pragma unroll
    for (int j = 0; j < 16; ++j) e[j] = ed[p + j];
    f16x4 v[16];
#pragma unroll
    for (int j = 0; j < 16; ++j) v[j] = supv[(size_t)e[j].x * 64 + lane];
#pragma unroll
    for (int j = 0; j < 16; ++j) {
      float wt = __int_as_float(e[j].y);
      acc[j & 3][0] += wt * (float)v[j][0];
      acc[j & 3][1] += wt * (float)v[j][1];
      acc[j & 3][2] += wt * (float)v[j][2];
      acc[j & 3][3] += wt * (float)v[j][3];
    }
  }
  for (; p + 4 <= p1; p += 4) {
    int2 e[4];
#pragma unroll
    for (int j = 0; j < 4; ++j) e[j] = ed[p + j];
    f16x4 v[4];
#pragma unroll
    for (int j = 0; j < 4; ++j) v[j] = supv[(size_t)e[j].x * 64 + lane];
#pragma unroll
    for (int j = 0; j < 4; ++j) {
      float wt = __int_as_float(e[j].y);
      acc[j][0] += wt * (float)v[j][0];
      acc[j][1] += wt * (float)v[j][1];
      acc[j][2] += wt * (float)v[j][2];
      acc[j][3] += wt * (float)v[j][3];
    }
  }
  for (; p < p1; ++p) {
    int2 e0 = ed[p];
    float wt = __int_as_float(e0.y);
    f16x4 v = supv[(size_t)e0.x * 64 + lane];
    acc[0][0] += wt * (float)v[0];
    acc[0][1] += wt * (float)v[1];
    acc[0][2] += wt * (float)v[2];
    acc[0][3] += wt * (float)v[3];
  }
  float4 b = *(const float4*)(bias + lane * 4);
  f16x4 r;
  r[0] = (f16)fmaxf(acc[0][0] + acc[1][0] + acc[2][0] + acc[3][0] + b.x, 0.f);
  r[1] = (f16)fmaxf(acc[0][1] + acc[1][1] + acc[2][1] + acc[3][1] + b.y, 0.f);
  r[2] = (f16)fmaxf(acc[0][2] + acc[1][2] + acc[2][2] + acc[3][2] + b.z, 0.f);
  r[3] = (f16)fmaxf(acc[0][3] + acc[1][3] + acc[2][3] + acc[3][3] + b.w, 0.f);
  *(f16x4*)(out + (size_t)wid * 256 + lane * 4) = r;
}

// ---------------- Aggregation D=64: one WAVE per row, quarter-wave edge slots ----

__global__ __launch_bounds__(256) void k_agg64(
    const f16* __restrict__ sup, const int* __restrict__ rowptr,
    const int2* __restrict__ ed, const float* __restrict__ bias,
    float* __restrict__ out, int n) {
  int wid = (blockIdx.x * THREADS + threadIdx.x) >> 6;
  int lane = threadIdx.x & 63;
  if (wid >= n) return;
  int p0 = rowptr[wid], p1 = rowptr[wid + 1];
  int q = lane >> 4;
  int hl = lane & 15;

  const f16x4* supv = (const f16x4*)sup;
  float acc[2][4] = {};
  int p = p0;
  for (; p + 32 <= p1; p += 32) {
    int2 e[8];
#pragma unroll
    for (int j = 0; j < 8; ++j) e[j] = ed[p + 4 * j + q];
    f16x4 v[8];
#pragma unroll
    for (int j = 0; j < 8; ++j) v[j] = supv[(size_t)e[j].x * 16 + hl];
#pragma unroll
    for (int j = 0; j < 8; ++j) {
      float wt = __int_as_float(e[j].y);
      acc[j & 1][0] += wt * (float)v[j][0];
      acc[j & 1][1] += wt * (float)v[j][1];
      acc[j & 1][2] += wt * (float)v[j][2];
      acc[j & 1][3] += wt * (float)v[j][3];
    }
  }
  for (; p + 4 <= p1; p += 4) {
    int2 e0 = ed[p + q];
    float wt = __int_as_float(e0.y);
    f16x4 v = supv[(size_t)e0.x * 16 + hl];
    acc[0][0] += wt * (float)v[0];
    acc[0][1] += wt * (float)v[1];
    acc[0][2] += wt * (float)v[2];
    acc[0][3] += wt * (float)v[3];
  }
  if (p < p1) {
    int idx = p + q;
    int c = 0;
    float wt = 0.f;
    if (idx < p1) {
      int2 e0 = ed[idx];
      c = e0.x;
      wt = __int_as_float(e0.y);
    }
    f16x4 v = supv[(size_t)c * 16 + hl];
    acc[0][0] += wt * (float)v[0];
    acc[0][1] += wt * (float)v[1];
    acc[0][2] += wt * (float)v[2];
    acc[0][3] += wt * (float)v[3];
  }
  float t0 = acc[0][0] + acc[1][0];
  float t1 = acc[0][1] + acc[1][1];
  float t2 = acc[0][2] + acc[1][2];
  float t3 = acc[0][3] + acc[1][3];
  t0 += __shfl_xor(t0, 16); t0 += __shfl_xor(t0, 32);
  t1 += __shfl_xor(t1, 16); t1 += __shfl_xor(t1, 32);
  t2 += __shfl_xor(t2, 16); t2 += __shfl_xor(t2, 32);
  t3 += __shfl_xor(t3, 16); t3 += __shfl_xor(t3, 32);
  if (q == 0) {
    float4 b = *(const float4*)(bias + hl * 4);
    float4 res;
    res.x = fmaxf(t0 + b.x, 0.f);
    res.y = fmaxf(t1 + b.y, 0.f);
    res.z = fmaxf(t2 + b.z, 0.f);
    res.w = fmaxf(t3 + b.w, 0.f);
    *(float4*)(out + (size_t)wid * 64 + hl * 4) = res;
  }
}

// ---------------- BN stats (240 blocks -> low atomic contention) ----------------

__global__ __launch_bounds__(256) void k_colstats(const f16* __restrict__ y,
                                                  float* __restrict__ sums, int n) {
  __shared__ float sh[8][256];
  int t = threadIdx.x;
  int cg = (t & 31) * 8;
  int rs = t >> 5;
  float s[8] = {}, s2[8] = {};
  for (int r = blockIdx.x * 8 + rs; r < n; r += gridDim.x * 8) {
    f16x8 v = *(const f16x8*)(y + (size_t)r * 256 + cg);
#pragma unroll
    for (int j = 0; j < 8; ++j) {
      float f = (float)v[j];
      s[j] += f;
      s2[j] += f * f;
    }
  }
#pragma unroll
  for (int j = 0; j < 8; ++j) sh[rs][cg + j] = s[j];
  __syncthreads();
  float tot = 0.f;
#pragma unroll
  for (int k = 0; k < 8; ++k) tot += sh[k][t];
  atomicAdd(&sums[t], tot);
  __syncthreads();
#pragma unroll
  for (int j = 0; j < 8; ++j) sh[rs][cg + j] = s2[j];
  __syncthreads();
  tot = 0.f;
#pragma unroll
  for (int k = 0; k < 8; ++k) tot += sh[k][t];
  atomicAdd(&sums[256 + t], tot);
}

// ---------------- launch ----------------

extern "C" void kernel_launch(void* const* d_in, const int* in_sizes, int n_in,
                              void* d_out, int out_size, void* d_ws, size_t ws_size,
                              hipStream_t stream) {
  const float* x = (const float*)d_in[0];
  const int* ei = (const int*)d_in[1];
  const float* ew = (const float*)d_in[2];
  const float* W1 = (const float*)d_in[3];
  const float* b1 = (const float*)d_in[4];
  const float* W2 = (const float*)d_in[5];
  const float* b2 = (const float*)d_in[6];
  const float* W3 = (const float*)d_in[7];
  const float* b3 = (const float*)d_in[8];
  float* out = (float*)d_out;

  const int N = in_sizes[0] / 512;  // 100000
  const int E = in_sizes[2];        // 3200000

  const int NB = (N + 127) >> BSH;            // 128-row buckets (782)
  const int NBLK = (E + EPB - 1) / EPB;       // binning blocks (391)
  const int scanN = NB * NBLK;
  const int ntiles = (scanN + 1023) / 1024;

  char* p = (char*)d_ws;
  auto alloc = [&](size_t bytes) {
    void* r = (void*)p;
    p += (bytes + 255) & ~(size_t)255;
    return r;
  };
  int* rowptr = (int*)alloc((size_t)(N + 1) * 4);
  int* cnt2d = (int*)alloc((size_t)scanN * 4);
  int* off2d = (int*)alloc((size_t)(scanN + 1) * 4);
  unsigned long long* tpub = (unsigned long long*)alloc((size_t)ntiles * 8);
  float* statZ = (float*)alloc(1024 * 4);
  float* sumsA = statZ;
  float* sumsB = statZ + 512;
  f16* Wt1 = (f16*)alloc((size_t)512 * 256 * 2);
  f16* Wt2 = (f16*)alloc((size_t)256 * 256 * 2);
  f16* Wt3 = (f16*)alloc((size_t)256 * 64 * 2);
  int2* temp = (int2*)alloc((size_t)E * 8);
  int2* ed = (int2*)alloc((size_t)E * 8);
  f16* sup = (f16*)alloc((size_t)N * 256 * 2);
  f16* act = (f16*)alloc((size_t)N * 256 * 2);

  const int* rows = ei;
  const int* colsIn = ei + E;

  const int gemmBlocks = (N + 127) / 128;
  const int aggBlocks = (N * 64 + THREADS - 1) / THREADS;

  // --- front: hist + Wt1/Wt2/Wt3 converts + zero stats (1 dispatch) ---
  k_front<<<NBLK + 832, 256, 0, stream>>>(
      rows, cnt2d, E, NBLK, NB, W1, Wt1, W2, Wt2, W3, Wt3, statZ, tpub, ntiles);

  // --- single-pass scan ---
  k_scanDL<<<ntiles, 256, 0, stream>>>(cnt2d, off2d, tpub, scanN);

  // --- bin + layer-1 GEMM (1 dispatch, independent halves) ---
  k_bin_gemm<<<NBLK + gemmBlocks, 256, 0, stream>>>(
      rows, colsIn, ew, off2d, temp, E, NBLK, NB, x, Wt1, sup, N);

  // --- scatter into final CSR ---
  k_scatter<<<NB, 256, 0, stream>>>(temp, off2d, rowptr, ed, N, E, NBLK, NB);

  // --- Layer 1 agg + BN1 stats (separate, low-contention) ---
  k_agg256<<<aggBlocks, 256, 0, stream>>>(sup, rowptr, ed, b1, act, N);
  k_colstats<<<240, 256, 0, stream>>>(act, sumsA, N);

  // --- Layer 2: GEMM folds BN1 into A-path; agg + BN2 stats ---
  k_gemm_mfma<256, true, true><<<gemmBlocks, 256, 0, stream>>>(
      act, Wt2, sup, N, 256, sumsA, N);
  k_agg256<<<aggBlocks, 256, 0, stream>>>(sup, rowptr, ed, b2, act, N);
  k_colstats<<<240, 256, 0, stream>>>(act, sumsB, N);

  // --- Layer 3: GEMM folds BN2; agg64 ---
  k_gemm_mfma<64, true, true><<<gemmBlocks, 256, 0, stream>>>(
      act, Wt3, sup, N, 256, sumsB, N);
  k_agg64<<<aggBlocks, 256, 0, stream>>>(sup, rowptr, ed, b3, out, N);
}